// Round 12
// baseline (205.506 us; speedup 1.0000x reference)
//
#include <hip/hip_runtime.h>
#include <hip/hip_fp16.h>
#include <math.h>

// SpinSphericalBlock: separable spin-weighted SHT -> channel mix -> inverse SHT
// -> complex BN (spin0 mean, via Parseval on G) -> magnitude-ReLU gating.
//
// Constants: B=8, RES=64, RES_OUT=32, L=15, SPINS_IN=(0,1), SPINS_OUT=(0,1,2),
// C_IN=64, C_OUT=128, NM=31. Output: out_size=3,145,728 float32 = Re(y),
// (b,t,p,s,d) row-major (established R0-R4).
//
// R12 (post-mortem R11): all kernels < 41us (invisible under fill-resets);
// ~55us of dur is fixed harness reset cost. Attacks: (1) F and G stored as
// fp16 (__half2 per complex; math fp32) -> ~40MB less traffic + half the VMEM
// instr count in theta_in/synth; (2) k_mix 1 b/block (1024 blocks) + 8-deep
// load pipeline -> 2x in-flight latency coverage.
//
//   K1 k_phi_tables: blocks<512: F[bt,m,iu] = sum_p x e^{-im phi_p} (radix-2)
//                    blocks>=512: Wigner tables (fp64 recurrence) + zero stats
//   K2 k_theta_in:   coeffs[b,k,iu]= sum_t A_in[i,k,t] F[b,t,m(k),iu]
//   K3 k_mix:        oc[b,k,sd]    = sum_iu coeffs * kernel[l(k),i,s,u,d]
//   K4 k_theta_out:  G[bt,m,sd]    = sum_l A_out[s,k,t] oc[b,k,sd]  + stats
//   K5 k_synth_final: y = BN(sum_m G e^{+im phi'_p}) -> gate -> Re(y) (radix-2)

#define PI_D 3.14159265358979323846

// ---------------- workspace layout (bytes) ----------------
#define OFF_A_IN    ((size_t)24320)     // 2*256*64 float    = 131072
#define OFF_A_OUT   ((size_t)155648)    // 3*256*32 float    = 98304
#define OFF_STATS   ((size_t)254208)    // 3*384 float       = 4608
#define OFF_R1      ((size_t)260608)    // F fp16 (8.1MB) then oc fp32 (6.3MB)
#define OFF_R2      ((size_t)25426688)  // coeffs fp32 (2.1MB) then G fp16 (12.2MB)

// ln(j!) for j=0..30
__constant__ double LF[31] = {
    0.0, 0.0, 0.6931471805599453, 1.791759469228055, 3.1780538303479458,
    4.787491742782046, 6.579251212010101, 8.525161361065415,
    10.604602902745251, 12.801827480081469, 15.104412573075516,
    17.502307845873887, 19.987214495661885, 22.552163853123425,
    25.19122118273868, 27.89927138384089, 30.671860106080672,
    33.50507345013689, 36.39544520803305, 39.339884187199495,
    42.335616460753485, 45.38013889847691, 48.47118135183523,
    51.60667556776438, 54.78472939811232, 58.00360522298052,
    61.261701761002, 64.55753862700634, 67.88974313718154,
    71.25703896716801, 74.65823634883016};

__device__ inline int isqrt_k(int k) {
    int l = (int)sqrtf((float)k + 0.5f);
    while (l * l > k) --l;
    while ((l + 1) * (l + 1) <= k) ++l;
    return l;
}

// d^l_{m,n}(theta) via seed term (1 exp + 2 log) + exact ratio recurrence.
__device__ double wigner_d_rec(int l, int m, int n, double theta) {
    int an = n < 0 ? -n : n;
    int am = m < 0 ? -m : m;
    if (l < an || l < am) return 0.0;
    int kmin = max(0, n - m), kmax = min(l + n, l - m);
    if (kmax < kmin) return 0.0;
    double cb = cos(0.5 * theta), sb = sin(0.5 * theta);
    double pref = 0.5 * (LF[l + m] + LF[l - m] + LF[l + n] + LF[l - n]);
    double lterm = pref
        - (LF[l + n - kmin] + LF[kmin] + LF[m - n + kmin] + LF[l - m - kmin])
        + (double)(2 * l + n - m - 2 * kmin) * log(cb)
        + (double)(m - n + 2 * kmin) * log(sb);
    double term = exp(lterm);
    if ((m - n + kmin) & 1) term = -term;
    double r = (sb * sb) / (cb * cb);
    double acc = term;
    for (int k = kmin; k < kmax; ++k) {
        term *= -((double)((l + n - k) * (l - m - k)) * r)
                / ((double)((k + 1) * (m - n + k + 1)));
        acc += term;
    }
    return acc;
}

// K1: fused phi-DFT (blocks 0..511) + table generation (blocks 512..626).
__global__ __launch_bounds__(512, 2) void k_phi_tables(const float* __restrict__ xr,
                                                       const float* __restrict__ xi,
                                                       __half2* __restrict__ F,
                                                       float* __restrict__ A_in,
                                                       float* __restrict__ A_out,
                                                       float* __restrict__ stats) {
    if (blockIdx.x >= 512) {
        int idx = (blockIdx.x - 512) * 512 + threadIdx.x;
        if (idx < 32768) {
            int t = idx & 63, k = (idx >> 6) & 255, i = idx >> 14;
            int l = isqrt_k(k);
            int m = k - l * l - l;
            double theta = ((double)t + 0.5) * PI_D / 64.0;
            double w = sin(theta) * (PI_D / 64.0) * (2.0 * PI_D / 64.0);
            double norm = sqrt((2.0 * l + 1.0) / (4.0 * PI_D));
            double d = wigner_d_rec(l, m, -i, theta);
            A_in[idx] = (float)(((m & 1) ? -1.0 : 1.0) * norm * w * d);
            return;
        }
        idx -= 32768;
        if (idx < 24576) {
            int t = idx & 31, k = (idx >> 5) & 255, s = idx >> 13;
            int l = isqrt_k(k);
            int m = k - l * l - l;
            double theta = ((double)t + 0.5) * PI_D / 32.0;
            double norm = sqrt((2.0 * l + 1.0) / (4.0 * PI_D));
            double d = wigner_d_rec(l, m, -s, theta);
            A_out[idx] = (float)(((m & 1) ? -1.0 : 1.0) * norm * d);
            return;
        }
        idx -= 24576;
        if (idx < 1152) stats[idx] = 0.f;
        return;
    }
    int bt = blockIdx.x;
    int iu = threadIdx.x & 127, mh = threadIdx.x >> 7;
    int mi0 = mh * 8;
    float2 acc[8], w[8], st[8];
#pragma unroll
    for (int j = 0; j < 8; ++j) {
        int m = mi0 + j - 15;
        float sy, sx;
        __sincosf(-(float)m * (float)(PI_D / 32.0), &sy, &sx);
        st[j] = make_float2(sx, sy);
        w[j] = make_float2(1.f, 0.f);
        acc[j] = make_float2(0.f, 0.f);
    }
    const float* xrb = xr + (size_t)bt * 8192 + iu;
    const float* xib = xi + (size_t)bt * 8192 + iu;
    for (int p = 0; p < 32; ++p) {
        float a  = xrb[(size_t)p * 128];
        float b  = xib[(size_t)p * 128];
        float a2 = xrb[(size_t)(p + 32) * 128];
        float b2 = xib[(size_t)(p + 32) * 128];
        float sar = a + a2, sai = b + b2;   // for even m
        float dar = a - a2, dai = b - b2;   // for odd m
#pragma unroll
        for (int j = 0; j < 8; ++j) {
            float ur = (j & 1) ? sar : dar;  // j odd -> m even
            float ui = (j & 1) ? sai : dai;
            acc[j].x += ur * w[j].x - ui * w[j].y;
            acc[j].y += ur * w[j].y + ui * w[j].x;
            float nx = w[j].x * st[j].x - w[j].y * st[j].y;
            w[j].y = w[j].x * st[j].y + w[j].y * st[j].x;
            w[j].x = nx;
        }
    }
    __half2* Fb = F + (size_t)bt * 31 * 128 + iu;
#pragma unroll
    for (int j = 0; j < 8; ++j) {
        int mi = mi0 + j;
        if (mi < 31) Fb[(size_t)mi * 128] = __float22half2_rn(acc[j]);
    }
}

// K2: theta contraction. grid (31, 8) = (mi, b), 512 threads (iu, th=t-quarter).
__global__ __launch_bounds__(512, 2) void k_theta_in(const __half2* __restrict__ F,
                                                     const float* __restrict__ A_in,
                                                     float2* __restrict__ coeffs) {
    __shared__ float A[2][16][64];      // 8 KB, zero-padded below |m|
    __shared__ float2 red[2][16][128];  // 32 KB reduction buffer
    int mi = blockIdx.x, b = blockIdx.y;
    int m = mi - 15;
    int am = m < 0 ? -m : m;
    int tid = threadIdx.x;
    for (int idx = tid; idx < 2048; idx += 512) {
        int i = idx >> 10, j = (idx >> 6) & 15, t = idx & 63;
        float v = 0.f;
        if (j >= am) v = A_in[((size_t)i * 256 + (j * j + j + m)) * 64 + t];
        A[i][j][t] = v;
    }
    __syncthreads();
    int iu = tid & 127, th = tid >> 7, i = iu >> 6;
    float2 acc[16];
#pragma unroll
    for (int j = 0; j < 16; ++j) acc[j] = make_float2(0.f, 0.f);
    const __half2* Fb = F + ((size_t)b * 64 * 31 + mi) * 128 + iu;
    for (int tt = 0; tt < 16; ++tt) {
        int t = th * 16 + tt;
        float2 f = __half22float2(Fb[(size_t)t * 31 * 128]);
#pragma unroll
        for (int j = 0; j < 16; ++j) {
            float a = A[i][j][t];
            acc[j].x += a * f.x;
            acc[j].y += a * f.y;
        }
    }
    if (th >= 2) {
#pragma unroll
        for (int j = 0; j < 16; ++j) red[th - 2][j][iu] = acc[j];
    }
    __syncthreads();
    if (th < 2) {
#pragma unroll
        for (int j = 0; j < 16; ++j) {
            float2 r = red[th][j][iu];
            acc[j].x += r.x;
            acc[j].y += r.y;
        }
    }
    __syncthreads();
    if (th == 1) {
#pragma unroll
        for (int j = 0; j < 16; ++j) red[0][j][iu] = acc[j];
    }
    __syncthreads();
    if (th == 0) {
#pragma unroll
        for (int j = 0; j < 16; ++j) {
            if (j >= am) {
                float2 r = red[0][j][iu];
                coeffs[((size_t)b * 256 + (j * j + j + m)) * 128 + iu] =
                    make_float2(acc[j].x + r.x, acc[j].y + r.y);
            }
        }
    }
}

// K3: channel mix v4. grid (128 kpair, 8 b), 384 threads = (kk 2)x(s 3)x(dp 64).
// 1 b per block; 8-deep double-buffered float2 kernel-load pipeline (16
// outstanding loads/thread). 1024 blocks, ~2 resident/CU at (384,3).
__global__ __launch_bounds__(384, 3) void k_mix(const float2* __restrict__ coeffs,
                                                const float* __restrict__ kr,
                                                const float* __restrict__ ki,
                                                float2* __restrict__ oc) {
    __shared__ float2 cs[2][128];  // [kk][iu], 2 KB
    int k0 = blockIdx.x * 2;
    int b = blockIdx.y;
    int tid = threadIdx.x;
    for (int idx = tid; idx < 256; idx += 384) {
        int kk = idx >> 7, iu = idx & 127;
        cs[kk][iu] = coeffs[((size_t)b * 256 + (k0 + kk)) * 128 + iu];
    }
    __syncthreads();
    int kk = tid / 192, r = tid % 192;
    int s = r >> 6, dp = r & 63;
    int k = k0 + kk;
    int l = isqrt_k(k);
    float2 acc0 = make_float2(0.f, 0.f), acc1 = make_float2(0.f, 0.f);
    for (int i = 0; i < 2; ++i) {
        const float2* krp = (const float2*)(kr + (size_t)(6 * l + 3 * i + s) * 8192) + dp;
        const float2* kip = (const float2*)(ki + (size_t)(6 * l + 3 * i + s) * 8192) + dp;
        float2 w0[8], w1[8];
#pragma unroll
        for (int j = 0; j < 8; ++j) { w0[j] = krp[(size_t)j * 64]; w1[j] = kip[(size_t)j * 64]; }
        for (int ub = 0; ub < 64; ub += 8) {
            float2 n0[8], n1[8];
            if (ub + 8 < 64) {
#pragma unroll
                for (int j = 0; j < 8; ++j) {
                    n0[j] = krp[(size_t)(ub + 8 + j) * 64];
                    n1[j] = kip[(size_t)(ub + 8 + j) * 64];
                }
            }
#pragma unroll
            for (int j = 0; j < 8; ++j) {
                int iu = i * 64 + ub + j;
                float2 wr = w0[j], wi = w1[j];
                float2 cv = cs[kk][iu];
                acc0.x += cv.x * wr.x - cv.y * wi.x;
                acc0.y += cv.x * wi.x + cv.y * wr.x;
                acc1.x += cv.x * wr.y - cv.y * wi.y;
                acc1.y += cv.x * wi.y + cv.y * wr.y;
            }
#pragma unroll
            for (int j = 0; j < 8; ++j) { w0[j] = n0[j]; w1[j] = n1[j]; }
        }
    }
    float4 stv = make_float4(acc0.x, acc0.y, acc1.x, acc1.y);
    *(float4*)&oc[((size_t)b * 256 + k) * 384 + s * 128 + 2 * dp] = stv;
}

// K4: theta expansion + stats; G written as fp16. grid (31, 8), 384 threads.
__global__ __launch_bounds__(384, 2) void k_theta_out(const float2* __restrict__ oc,
                                                      const float* __restrict__ A_out,
                                                      __half2* __restrict__ G,
                                                      float* __restrict__ ssr,
                                                      float* __restrict__ ssi,
                                                      float* __restrict__ ssq) {
    __shared__ float Ao[3][16][32];  // 6KB
    int mi = blockIdx.x, b = blockIdx.y;
    int m = mi - 15;
    int am = m < 0 ? -m : m;
    int tid = threadIdx.x;
    for (int idx = tid; idx < 1536; idx += 384) {
        int s = idx >> 9, j = (idx >> 5) & 15, t = idx & 31;
        float v = 0.f;
        if (j >= am) v = A_out[((size_t)s * 256 + (j * j + j + m)) * 32 + t];
        Ao[s][j][t] = v;
    }
    __syncthreads();
    int s = tid >> 7;
    float2 c[16];
#pragma unroll
    for (int j = 0; j < 16; ++j) {
        c[j] = make_float2(0.f, 0.f);
        if (j >= am) c[j] = oc[((size_t)b * 256 + (j * j + j + m)) * 384 + tid];
    }
    float sq = 0.f, sr = 0.f, si = 0.f;
    for (int t = 0; t < 32; ++t) {
        float fr = 0.f, fi = 0.f;
#pragma unroll
        for (int j = 0; j < 16; ++j) {
            float a = Ao[s][j][t];
            fr += a * c[j].x;
            fi += a * c[j].y;
        }
        G[(((size_t)b * 32 + t) * 31 + mi) * 384 + tid] =
            __float22half2_rn(make_float2(fr, fi));
        sq += fr * fr + fi * fi;
        if (mi == 15) { sr += fr; si += fi; }
    }
    atomicAdd(&ssq[tid], sq);
    if (mi == 15) {
        atomicAdd(&ssr[tid], sr);
        atomicAdd(&ssi[tid], si);
    }
}

// K5: phi synthesis + BN + gate, radix-2 folded; G read as fp16.
__global__ __launch_bounds__(384, 1) void k_synth_final(const __half2* __restrict__ G,
                                                        const float* __restrict__ ssr,
                                                        const float* __restrict__ ssi,
                                                        const float* __restrict__ ssq,
                                                        const float* __restrict__ gamma,
                                                        const float* __restrict__ betar,
                                                        const float* __restrict__ betai,
                                                        const float* __restrict__ bias,
                                                        float* __restrict__ out) {
    int bt = blockIdx.x;
    int sd = threadIdx.x, s = sd >> 7;
    float2 g[31], st[31];
#pragma unroll
    for (int mi = 0; mi < 31; ++mi) {
        g[mi] = __half22float2(G[((size_t)bt * 31 + mi) * 384 + sd]);
        float sy, sx;
        __sincosf((float)(mi - 15) * (float)(PI_D / 16.0), &sy, &sx);
        st[mi] = make_float2(sx, sy);
    }
    const float invN = 1.0f / 256.0f;
    float mur = 0.f, mui = 0.f;
    if (s == 0) { mur = ssr[sd] * invN; mui = ssi[sd] * invN; }
    float var = ssq[sd] * invN - (mur * mur + mui * mui);
    float scale = gamma[sd] / sqrtf(var + 1e-5f);
    float br = (s == 0) ? betar[sd] : 0.f;
    float bi = (s == 0) ? betai[sd] : 0.f;
    float bb = bias[sd];
    float* ob = out + (size_t)bt * 32 * 384 + sd;
    for (int p = 0; p < 16; ++p) {
        float fr = 0.f, fi = 0.f, fr2 = 0.f, fi2 = 0.f;
#pragma unroll
        for (int mi = 0; mi < 31; ++mi) {
            fr += g[mi].x;
            fi += g[mi].y;
            if (mi & 1) { fr2 += g[mi].x; fi2 += g[mi].y; }  // m even
            else        { fr2 -= g[mi].x; fi2 -= g[mi].y; }  // m odd
        }
        {
            float yr = (fr - mur) * scale + br;
            float yi = (fi - mui) * scale + bi;
            float mag = sqrtf(yr * yr + yi * yi);
            float f = fmaxf(mag + bb, 0.f) / (mag + 1e-6f);
            ob[(size_t)p * 384] = yr * f;
        }
        {
            float yr = (fr2 - mur) * scale + br;
            float yi = (fi2 - mui) * scale + bi;
            float mag = sqrtf(yr * yr + yi * yi);
            float f = fmaxf(mag + bb, 0.f) / (mag + 1e-6f);
            ob[(size_t)(p + 16) * 384] = yr * f;
        }
#pragma unroll
        for (int mi = 0; mi < 31; ++mi) {
            float nx = g[mi].x * st[mi].x - g[mi].y * st[mi].y;
            g[mi].y = g[mi].x * st[mi].y + g[mi].y * st[mi].x;
            g[mi].x = nx;
        }
    }
}

extern "C" void kernel_launch(void* const* d_in, const int* in_sizes, int n_in,
                              void* d_out, int out_size, void* d_ws, size_t ws_size,
                              hipStream_t stream) {
    const float* xr    = (const float*)d_in[0];
    const float* xi    = (const float*)d_in[1];
    const float* kr    = (const float*)d_in[2];
    const float* ki    = (const float*)d_in[3];
    const float* gamma = (const float*)d_in[4];
    const float* betar = (const float*)d_in[5];
    const float* betai = (const float*)d_in[6];
    const float* bias  = (const float*)d_in[7];
    float* out = (float*)d_out;

    char* ws = (char*)d_ws;
    float*   A_in   = (float*)(ws + OFF_A_IN);
    float*   A_out  = (float*)(ws + OFF_A_OUT);
    float*   stats  = (float*)(ws + OFF_STATS);
    float*   ssr    = stats;
    float*   ssi    = stats + 384;
    float*   ssq    = stats + 768;
    __half2* F      = (__half2*)(ws + OFF_R1);  // then oc (fp32)
    float2*  oc     = (float2*)(ws + OFF_R1);
    float2*  coeffs = (float2*)(ws + OFF_R2);   // then G (fp16)
    __half2* G      = (__half2*)(ws + OFF_R2);

    k_phi_tables<<<627, 512, 0, stream>>>(xr, xi, F, A_in, A_out, stats);
    k_theta_in<<<dim3(31, 8), 512, 0, stream>>>(F, A_in, coeffs);
    k_mix<<<dim3(128, 8), 384, 0, stream>>>(coeffs, kr, ki, oc);
    k_theta_out<<<dim3(31, 8), 384, 0, stream>>>(oc, A_out, G, ssr, ssi, ssq);
    k_synth_final<<<256, 384, 0, stream>>>(G, ssr, ssi, ssq,
                                           gamma, betar, betai, bias, out);
}

// Round 13
// 181.600 us; speedup vs baseline: 1.1316x; 1.1316x over previous
//
#include <hip/hip_runtime.h>
#include <hip/hip_fp16.h>
#include <math.h>

// SpinSphericalBlock: separable spin-weighted SHT -> channel mix -> inverse SHT
// -> complex BN (spin0 mean, via Parseval on G) -> magnitude-ReLU gating.
//
// Constants: B=8, RES=64, RES_OUT=32, L=15, SPINS_IN=(0,1), SPINS_OUT=(0,1,2),
// C_IN=64, C_OUT=128, NM=31. Output: out_size=3,145,728 float32 = Re(y),
// (b,t,p,s,d) row-major (established R0-R4).
//
// R13 (post-mortem R12): the 1-b/block k_mix regressed (FETCH 22.5->51 MB,
// kernel-weight re-read doubled; 64us). Reverted to R11's k_mix (2k x 2b
// blocks, 4-deep pipeline) which measured <=41us. fp16 F/G kept (neutral
// traffic win, absmax unchanged).
//
//   K1 k_phi_tables: blocks<512: F[bt,m,iu] = sum_p x e^{-im phi_p} (radix-2)
//                    blocks>=512: Wigner tables (fp64 recurrence) + zero stats
//   K2 k_theta_in:   coeffs[b,k,iu]= sum_t A_in[i,k,t] F[b,t,m(k),iu]
//   K3 k_mix:        oc[b,k,sd]    = sum_iu coeffs * kernel[l(k),i,s,u,d]
//   K4 k_theta_out:  G[bt,m,sd]    = sum_l A_out[s,k,t] oc[b,k,sd]  + stats
//   K5 k_synth_final: y = BN(sum_m G e^{+im phi'_p}) -> gate -> Re(y) (radix-2)

#define PI_D 3.14159265358979323846

// ---------------- workspace layout (bytes) ----------------
#define OFF_A_IN    ((size_t)24320)     // 2*256*64 float    = 131072
#define OFF_A_OUT   ((size_t)155648)    // 3*256*32 float    = 98304
#define OFF_STATS   ((size_t)254208)    // 3*384 float       = 4608
#define OFF_R1      ((size_t)260608)    // F fp16 (8.1MB) then oc fp32 (6.3MB)
#define OFF_R2      ((size_t)25426688)  // coeffs fp32 (2.1MB) then G fp16 (12.2MB)

// ln(j!) for j=0..30
__constant__ double LF[31] = {
    0.0, 0.0, 0.6931471805599453, 1.791759469228055, 3.1780538303479458,
    4.787491742782046, 6.579251212010101, 8.525161361065415,
    10.604602902745251, 12.801827480081469, 15.104412573075516,
    17.502307845873887, 19.987214495661885, 22.552163853123425,
    25.19122118273868, 27.89927138384089, 30.671860106080672,
    33.50507345013689, 36.39544520803305, 39.339884187199495,
    42.335616460753485, 45.38013889847691, 48.47118135183523,
    51.60667556776438, 54.78472939811232, 58.00360522298052,
    61.261701761002, 64.55753862700634, 67.88974313718154,
    71.25703896716801, 74.65823634883016};

__device__ inline int isqrt_k(int k) {
    int l = (int)sqrtf((float)k + 0.5f);
    while (l * l > k) --l;
    while ((l + 1) * (l + 1) <= k) ++l;
    return l;
}

// d^l_{m,n}(theta) via seed term (1 exp + 2 log) + exact ratio recurrence.
__device__ double wigner_d_rec(int l, int m, int n, double theta) {
    int an = n < 0 ? -n : n;
    int am = m < 0 ? -m : m;
    if (l < an || l < am) return 0.0;
    int kmin = max(0, n - m), kmax = min(l + n, l - m);
    if (kmax < kmin) return 0.0;
    double cb = cos(0.5 * theta), sb = sin(0.5 * theta);
    double pref = 0.5 * (LF[l + m] + LF[l - m] + LF[l + n] + LF[l - n]);
    double lterm = pref
        - (LF[l + n - kmin] + LF[kmin] + LF[m - n + kmin] + LF[l - m - kmin])
        + (double)(2 * l + n - m - 2 * kmin) * log(cb)
        + (double)(m - n + 2 * kmin) * log(sb);
    double term = exp(lterm);
    if ((m - n + kmin) & 1) term = -term;
    double r = (sb * sb) / (cb * cb);
    double acc = term;
    for (int k = kmin; k < kmax; ++k) {
        term *= -((double)((l + n - k) * (l - m - k)) * r)
                / ((double)((k + 1) * (m - n + k + 1)));
        acc += term;
    }
    return acc;
}

// K1: fused phi-DFT (blocks 0..511) + table generation (blocks 512..626).
__global__ __launch_bounds__(512, 2) void k_phi_tables(const float* __restrict__ xr,
                                                       const float* __restrict__ xi,
                                                       __half2* __restrict__ F,
                                                       float* __restrict__ A_in,
                                                       float* __restrict__ A_out,
                                                       float* __restrict__ stats) {
    if (blockIdx.x >= 512) {
        int idx = (blockIdx.x - 512) * 512 + threadIdx.x;
        if (idx < 32768) {
            int t = idx & 63, k = (idx >> 6) & 255, i = idx >> 14;
            int l = isqrt_k(k);
            int m = k - l * l - l;
            double theta = ((double)t + 0.5) * PI_D / 64.0;
            double w = sin(theta) * (PI_D / 64.0) * (2.0 * PI_D / 64.0);
            double norm = sqrt((2.0 * l + 1.0) / (4.0 * PI_D));
            double d = wigner_d_rec(l, m, -i, theta);
            A_in[idx] = (float)(((m & 1) ? -1.0 : 1.0) * norm * w * d);
            return;
        }
        idx -= 32768;
        if (idx < 24576) {
            int t = idx & 31, k = (idx >> 5) & 255, s = idx >> 13;
            int l = isqrt_k(k);
            int m = k - l * l - l;
            double theta = ((double)t + 0.5) * PI_D / 32.0;
            double norm = sqrt((2.0 * l + 1.0) / (4.0 * PI_D));
            double d = wigner_d_rec(l, m, -s, theta);
            A_out[idx] = (float)(((m & 1) ? -1.0 : 1.0) * norm * d);
            return;
        }
        idx -= 24576;
        if (idx < 1152) stats[idx] = 0.f;
        return;
    }
    int bt = blockIdx.x;
    int iu = threadIdx.x & 127, mh = threadIdx.x >> 7;
    int mi0 = mh * 8;
    float2 acc[8], w[8], st[8];
#pragma unroll
    for (int j = 0; j < 8; ++j) {
        int m = mi0 + j - 15;
        float sy, sx;
        __sincosf(-(float)m * (float)(PI_D / 32.0), &sy, &sx);
        st[j] = make_float2(sx, sy);
        w[j] = make_float2(1.f, 0.f);
        acc[j] = make_float2(0.f, 0.f);
    }
    const float* xrb = xr + (size_t)bt * 8192 + iu;
    const float* xib = xi + (size_t)bt * 8192 + iu;
    for (int p = 0; p < 32; ++p) {
        float a  = xrb[(size_t)p * 128];
        float b  = xib[(size_t)p * 128];
        float a2 = xrb[(size_t)(p + 32) * 128];
        float b2 = xib[(size_t)(p + 32) * 128];
        float sar = a + a2, sai = b + b2;   // for even m
        float dar = a - a2, dai = b - b2;   // for odd m
#pragma unroll
        for (int j = 0; j < 8; ++j) {
            float ur = (j & 1) ? sar : dar;  // j odd -> m even
            float ui = (j & 1) ? sai : dai;
            acc[j].x += ur * w[j].x - ui * w[j].y;
            acc[j].y += ur * w[j].y + ui * w[j].x;
            float nx = w[j].x * st[j].x - w[j].y * st[j].y;
            w[j].y = w[j].x * st[j].y + w[j].y * st[j].x;
            w[j].x = nx;
        }
    }
    __half2* Fb = F + (size_t)bt * 31 * 128 + iu;
#pragma unroll
    for (int j = 0; j < 8; ++j) {
        int mi = mi0 + j;
        if (mi < 31) Fb[(size_t)mi * 128] = __float22half2_rn(acc[j]);
    }
}

// K2: theta contraction. grid (31, 8) = (mi, b), 512 threads (iu, th=t-quarter).
__global__ __launch_bounds__(512, 2) void k_theta_in(const __half2* __restrict__ F,
                                                     const float* __restrict__ A_in,
                                                     float2* __restrict__ coeffs) {
    __shared__ float A[2][16][64];      // 8 KB, zero-padded below |m|
    __shared__ float2 red[2][16][128];  // 32 KB reduction buffer
    int mi = blockIdx.x, b = blockIdx.y;
    int m = mi - 15;
    int am = m < 0 ? -m : m;
    int tid = threadIdx.x;
    for (int idx = tid; idx < 2048; idx += 512) {
        int i = idx >> 10, j = (idx >> 6) & 15, t = idx & 63;
        float v = 0.f;
        if (j >= am) v = A_in[((size_t)i * 256 + (j * j + j + m)) * 64 + t];
        A[i][j][t] = v;
    }
    __syncthreads();
    int iu = tid & 127, th = tid >> 7, i = iu >> 6;
    float2 acc[16];
#pragma unroll
    for (int j = 0; j < 16; ++j) acc[j] = make_float2(0.f, 0.f);
    const __half2* Fb = F + ((size_t)b * 64 * 31 + mi) * 128 + iu;
    for (int tt = 0; tt < 16; ++tt) {
        int t = th * 16 + tt;
        float2 f = __half22float2(Fb[(size_t)t * 31 * 128]);
#pragma unroll
        for (int j = 0; j < 16; ++j) {
            float a = A[i][j][t];
            acc[j].x += a * f.x;
            acc[j].y += a * f.y;
        }
    }
    if (th >= 2) {
#pragma unroll
        for (int j = 0; j < 16; ++j) red[th - 2][j][iu] = acc[j];
    }
    __syncthreads();
    if (th < 2) {
#pragma unroll
        for (int j = 0; j < 16; ++j) {
            float2 r = red[th][j][iu];
            acc[j].x += r.x;
            acc[j].y += r.y;
        }
    }
    __syncthreads();
    if (th == 1) {
#pragma unroll
        for (int j = 0; j < 16; ++j) red[0][j][iu] = acc[j];
    }
    __syncthreads();
    if (th == 0) {
#pragma unroll
        for (int j = 0; j < 16; ++j) {
            if (j >= am) {
                float2 r = red[0][j][iu];
                coeffs[((size_t)b * 256 + (j * j + j + m)) * 128 + iu] =
                    make_float2(acc[j].x + r.x, acc[j].y + r.y);
            }
        }
    }
}

// K3: channel mix (R11 version — best measured, <=41us). grid (128 kpair, 4 bq),
// 384 threads = (kk 2)x(s 3)x(dp 64). Thread: 2 sd (float2 kernel loads) x 2 b.
// Manual 4-deep double-buffered kernel-load pipeline; launch_bounds(384,3).
__global__ __launch_bounds__(384, 3) void k_mix(const float2* __restrict__ coeffs,
                                                const float* __restrict__ kr,
                                                const float* __restrict__ ki,
                                                float2* __restrict__ oc) {
    __shared__ float2 cs[2][2][128];  // [kk][bb][iu], 4 KB
    int k0 = blockIdx.x * 2;
    int b0 = blockIdx.y * 2;
    int tid = threadIdx.x;
    for (int idx = tid; idx < 512; idx += 384) {
        int kk = idx >> 8, bb = (idx >> 7) & 1, iu = idx & 127;
        cs[kk][bb][iu] = coeffs[((size_t)(b0 + bb) * 256 + (k0 + kk)) * 128 + iu];
    }
    __syncthreads();
    int kk = tid / 192, r = tid % 192;
    int s = r >> 6, dp = r & 63;
    int k = k0 + kk;
    int l = isqrt_k(k);
    float2 acc[2][2];
#pragma unroll
    for (int bb = 0; bb < 2; ++bb) {
        acc[bb][0] = make_float2(0.f, 0.f);
        acc[bb][1] = make_float2(0.f, 0.f);
    }
    for (int i = 0; i < 2; ++i) {
        const float2* krp = (const float2*)(kr + (size_t)(6 * l + 3 * i + s) * 8192) + dp;
        const float2* kip = (const float2*)(ki + (size_t)(6 * l + 3 * i + s) * 8192) + dp;
        float2 w0[4], w1[4];
#pragma unroll
        for (int j = 0; j < 4; ++j) { w0[j] = krp[(size_t)j * 64]; w1[j] = kip[(size_t)j * 64]; }
        for (int ub = 0; ub < 64; ub += 4) {
            float2 n0[4], n1[4];
            if (ub + 4 < 64) {
#pragma unroll
                for (int j = 0; j < 4; ++j) {
                    n0[j] = krp[(size_t)(ub + 4 + j) * 64];
                    n1[j] = kip[(size_t)(ub + 4 + j) * 64];
                }
            }
#pragma unroll
            for (int j = 0; j < 4; ++j) {
                int iu = i * 64 + ub + j;
                float2 wr = w0[j], wi = w1[j];
#pragma unroll
                for (int bb = 0; bb < 2; ++bb) {
                    float2 cv = cs[kk][bb][iu];
                    acc[bb][0].x += cv.x * wr.x - cv.y * wi.x;
                    acc[bb][0].y += cv.x * wi.x + cv.y * wr.x;
                    acc[bb][1].x += cv.x * wr.y - cv.y * wi.y;
                    acc[bb][1].y += cv.x * wi.y + cv.y * wr.y;
                }
            }
#pragma unroll
            for (int j = 0; j < 4; ++j) { w0[j] = n0[j]; w1[j] = n1[j]; }
        }
    }
#pragma unroll
    for (int bb = 0; bb < 2; ++bb) {
        float4 stv = make_float4(acc[bb][0].x, acc[bb][0].y, acc[bb][1].x, acc[bb][1].y);
        *(float4*)&oc[((size_t)(b0 + bb) * 256 + k) * 384 + s * 128 + 2 * dp] = stv;
    }
}

// K4: theta expansion + stats; G written as fp16. grid (31, 8), 384 threads.
__global__ __launch_bounds__(384, 2) void k_theta_out(const float2* __restrict__ oc,
                                                      const float* __restrict__ A_out,
                                                      __half2* __restrict__ G,
                                                      float* __restrict__ ssr,
                                                      float* __restrict__ ssi,
                                                      float* __restrict__ ssq) {
    __shared__ float Ao[3][16][32];  // 6KB
    int mi = blockIdx.x, b = blockIdx.y;
    int m = mi - 15;
    int am = m < 0 ? -m : m;
    int tid = threadIdx.x;
    for (int idx = tid; idx < 1536; idx += 384) {
        int s = idx >> 9, j = (idx >> 5) & 15, t = idx & 31;
        float v = 0.f;
        if (j >= am) v = A_out[((size_t)s * 256 + (j * j + j + m)) * 32 + t];
        Ao[s][j][t] = v;
    }
    __syncthreads();
    int s = tid >> 7;
    float2 c[16];
#pragma unroll
    for (int j = 0; j < 16; ++j) {
        c[j] = make_float2(0.f, 0.f);
        if (j >= am) c[j] = oc[((size_t)b * 256 + (j * j + j + m)) * 384 + tid];
    }
    float sq = 0.f, sr = 0.f, si = 0.f;
    for (int t = 0; t < 32; ++t) {
        float fr = 0.f, fi = 0.f;
#pragma unroll
        for (int j = 0; j < 16; ++j) {
            float a = Ao[s][j][t];
            fr += a * c[j].x;
            fi += a * c[j].y;
        }
        G[(((size_t)b * 32 + t) * 31 + mi) * 384 + tid] =
            __float22half2_rn(make_float2(fr, fi));
        sq += fr * fr + fi * fi;
        if (mi == 15) { sr += fr; si += fi; }
    }
    atomicAdd(&ssq[tid], sq);
    if (mi == 15) {
        atomicAdd(&ssr[tid], sr);
        atomicAdd(&ssi[tid], si);
    }
}

// K5: phi synthesis + BN + gate, radix-2 folded; G read as fp16.
__global__ __launch_bounds__(384, 1) void k_synth_final(const __half2* __restrict__ G,
                                                        const float* __restrict__ ssr,
                                                        const float* __restrict__ ssi,
                                                        const float* __restrict__ ssq,
                                                        const float* __restrict__ gamma,
                                                        const float* __restrict__ betar,
                                                        const float* __restrict__ betai,
                                                        const float* __restrict__ bias,
                                                        float* __restrict__ out) {
    int bt = blockIdx.x;
    int sd = threadIdx.x, s = sd >> 7;
    float2 g[31], st[31];
#pragma unroll
    for (int mi = 0; mi < 31; ++mi) {
        g[mi] = __half22float2(G[((size_t)bt * 31 + mi) * 384 + sd]);
        float sy, sx;
        __sincosf((float)(mi - 15) * (float)(PI_D / 16.0), &sy, &sx);
        st[mi] = make_float2(sx, sy);
    }
    const float invN = 1.0f / 256.0f;
    float mur = 0.f, mui = 0.f;
    if (s == 0) { mur = ssr[sd] * invN; mui = ssi[sd] * invN; }
    float var = ssq[sd] * invN - (mur * mur + mui * mui);
    float scale = gamma[sd] / sqrtf(var + 1e-5f);
    float br = (s == 0) ? betar[sd] : 0.f;
    float bi = (s == 0) ? betai[sd] : 0.f;
    float bb = bias[sd];
    float* ob = out + (size_t)bt * 32 * 384 + sd;
    for (int p = 0; p < 16; ++p) {
        float fr = 0.f, fi = 0.f, fr2 = 0.f, fi2 = 0.f;
#pragma unroll
        for (int mi = 0; mi < 31; ++mi) {
            fr += g[mi].x;
            fi += g[mi].y;
            if (mi & 1) { fr2 += g[mi].x; fi2 += g[mi].y; }  // m even
            else        { fr2 -= g[mi].x; fi2 -= g[mi].y; }  // m odd
        }
        {
            float yr = (fr - mur) * scale + br;
            float yi = (fi - mui) * scale + bi;
            float mag = sqrtf(yr * yr + yi * yi);
            float f = fmaxf(mag + bb, 0.f) / (mag + 1e-6f);
            ob[(size_t)p * 384] = yr * f;
        }
        {
            float yr = (fr2 - mur) * scale + br;
            float yi = (fi2 - mui) * scale + bi;
            float mag = sqrtf(yr * yr + yi * yi);
            float f = fmaxf(mag + bb, 0.f) / (mag + 1e-6f);
            ob[(size_t)(p + 16) * 384] = yr * f;
        }
#pragma unroll
        for (int mi = 0; mi < 31; ++mi) {
            float nx = g[mi].x * st[mi].x - g[mi].y * st[mi].y;
            g[mi].y = g[mi].x * st[mi].y + g[mi].y * st[mi].x;
            g[mi].x = nx;
        }
    }
}

extern "C" void kernel_launch(void* const* d_in, const int* in_sizes, int n_in,
                              void* d_out, int out_size, void* d_ws, size_t ws_size,
                              hipStream_t stream) {
    const float* xr    = (const float*)d_in[0];
    const float* xi    = (const float*)d_in[1];
    const float* kr    = (const float*)d_in[2];
    const float* ki    = (const float*)d_in[3];
    const float* gamma = (const float*)d_in[4];
    const float* betar = (const float*)d_in[5];
    const float* betai = (const float*)d_in[6];
    const float* bias  = (const float*)d_in[7];
    float* out = (float*)d_out;

    char* ws = (char*)d_ws;
    float*   A_in   = (float*)(ws + OFF_A_IN);
    float*   A_out  = (float*)(ws + OFF_A_OUT);
    float*   stats  = (float*)(ws + OFF_STATS);
    float*   ssr    = stats;
    float*   ssi    = stats + 384;
    float*   ssq    = stats + 768;
    __half2* F      = (__half2*)(ws + OFF_R1);  // then oc (fp32)
    float2*  oc     = (float2*)(ws + OFF_R1);
    float2*  coeffs = (float2*)(ws + OFF_R2);   // then G (fp16)
    __half2* G      = (__half2*)(ws + OFF_R2);

    k_phi_tables<<<627, 512, 0, stream>>>(xr, xi, F, A_in, A_out, stats);
    k_theta_in<<<dim3(31, 8), 512, 0, stream>>>(F, A_in, coeffs);
    k_mix<<<dim3(128, 4), 384, 0, stream>>>(coeffs, kr, ki, oc);
    k_theta_out<<<dim3(31, 8), 384, 0, stream>>>(oc, A_out, G, ssr, ssi, ssq);
    k_synth_final<<<256, 384, 0, stream>>>(G, ssr, ssi, ssq,
                                           gamma, betar, betai, bias, out);
}

// Round 14
// 180.468 us; speedup vs baseline: 1.1387x; 1.0063x over previous
//
#include <hip/hip_runtime.h>
#include <hip/hip_fp16.h>
#include <math.h>

// SpinSphericalBlock: separable spin-weighted SHT -> channel mix -> inverse SHT
// -> complex BN (spin0 mean, via Parseval on G) -> magnitude-ReLU gating.
//
// Constants: B=8, RES=64, RES_OUT=32, L=15, SPINS_IN=(0,1), SPINS_OUT=(0,1,2),
// C_IN=64, C_OUT=128, NM=31. Output: out_size=3,145,728 float32 = Re(y),
// (b,t,p,s,d) row-major (established R0-R4).
//
// R14 (post-mortem R13, 181.6us, all kernels under the 41us fill floor):
// (1) coeffs and oc stored fp16 (__half2 per complex, fp32 math) -> halves
// VMEM instrs in K2-write/K3-stage/K3-write/K4-read; (2) k_mix i-loop
// flattened so the 4-deep load pipeline never drains at the i=0->1 boundary.
//
//   K1 k_phi_tables: blocks<512: F[bt,m,iu] = sum_p x e^{-im phi_p} (radix-2)
//                    blocks>=512: Wigner tables (fp64 recurrence) + zero stats
//   K2 k_theta_in:   coeffs[b,k,iu]= sum_t A_in[i,k,t] F[b,t,m(k),iu]
//   K3 k_mix:        oc[b,k,sd]    = sum_iu coeffs * kernel[l(k),i,s,u,d]
//   K4 k_theta_out:  G[bt,m,sd]    = sum_l A_out[s,k,t] oc[b,k,sd]  + stats
//   K5 k_synth_final: y = BN(sum_m G e^{+im phi'_p}) -> gate -> Re(y) (radix-2)

#define PI_D 3.14159265358979323846

// ---------------- workspace layout (bytes) ----------------
#define OFF_A_IN    ((size_t)24320)     // 2*256*64 float    = 131072
#define OFF_A_OUT   ((size_t)155648)    // 3*256*32 float    = 98304
#define OFF_STATS   ((size_t)254208)    // 3*384 float       = 4608
#define OFF_R1      ((size_t)260608)    // F fp16 (8.1MB) then oc fp16 (3.1MB)
#define OFF_R2      ((size_t)25426688)  // coeffs fp16 (1MB) then G fp16 (12.2MB)

// ln(j!) for j=0..30
__constant__ double LF[31] = {
    0.0, 0.0, 0.6931471805599453, 1.791759469228055, 3.1780538303479458,
    4.787491742782046, 6.579251212010101, 8.525161361065415,
    10.604602902745251, 12.801827480081469, 15.104412573075516,
    17.502307845873887, 19.987214495661885, 22.552163853123425,
    25.19122118273868, 27.89927138384089, 30.671860106080672,
    33.50507345013689, 36.39544520803305, 39.339884187199495,
    42.335616460753485, 45.38013889847691, 48.47118135183523,
    51.60667556776438, 54.78472939811232, 58.00360522298052,
    61.261701761002, 64.55753862700634, 67.88974313718154,
    71.25703896716801, 74.65823634883016};

__device__ inline int isqrt_k(int k) {
    int l = (int)sqrtf((float)k + 0.5f);
    while (l * l > k) --l;
    while ((l + 1) * (l + 1) <= k) ++l;
    return l;
}

// d^l_{m,n}(theta) via seed term (1 exp + 2 log) + exact ratio recurrence.
__device__ double wigner_d_rec(int l, int m, int n, double theta) {
    int an = n < 0 ? -n : n;
    int am = m < 0 ? -m : m;
    if (l < an || l < am) return 0.0;
    int kmin = max(0, n - m), kmax = min(l + n, l - m);
    if (kmax < kmin) return 0.0;
    double cb = cos(0.5 * theta), sb = sin(0.5 * theta);
    double pref = 0.5 * (LF[l + m] + LF[l - m] + LF[l + n] + LF[l - n]);
    double lterm = pref
        - (LF[l + n - kmin] + LF[kmin] + LF[m - n + kmin] + LF[l - m - kmin])
        + (double)(2 * l + n - m - 2 * kmin) * log(cb)
        + (double)(m - n + 2 * kmin) * log(sb);
    double term = exp(lterm);
    if ((m - n + kmin) & 1) term = -term;
    double r = (sb * sb) / (cb * cb);
    double acc = term;
    for (int k = kmin; k < kmax; ++k) {
        term *= -((double)((l + n - k) * (l - m - k)) * r)
                / ((double)((k + 1) * (m - n + k + 1)));
        acc += term;
    }
    return acc;
}

// K1: fused phi-DFT (blocks 0..511) + table generation (blocks 512..626).
__global__ __launch_bounds__(512, 2) void k_phi_tables(const float* __restrict__ xr,
                                                       const float* __restrict__ xi,
                                                       __half2* __restrict__ F,
                                                       float* __restrict__ A_in,
                                                       float* __restrict__ A_out,
                                                       float* __restrict__ stats) {
    if (blockIdx.x >= 512) {
        int idx = (blockIdx.x - 512) * 512 + threadIdx.x;
        if (idx < 32768) {
            int t = idx & 63, k = (idx >> 6) & 255, i = idx >> 14;
            int l = isqrt_k(k);
            int m = k - l * l - l;
            double theta = ((double)t + 0.5) * PI_D / 64.0;
            double w = sin(theta) * (PI_D / 64.0) * (2.0 * PI_D / 64.0);
            double norm = sqrt((2.0 * l + 1.0) / (4.0 * PI_D));
            double d = wigner_d_rec(l, m, -i, theta);
            A_in[idx] = (float)(((m & 1) ? -1.0 : 1.0) * norm * w * d);
            return;
        }
        idx -= 32768;
        if (idx < 24576) {
            int t = idx & 31, k = (idx >> 5) & 255, s = idx >> 13;
            int l = isqrt_k(k);
            int m = k - l * l - l;
            double theta = ((double)t + 0.5) * PI_D / 32.0;
            double norm = sqrt((2.0 * l + 1.0) / (4.0 * PI_D));
            double d = wigner_d_rec(l, m, -s, theta);
            A_out[idx] = (float)(((m & 1) ? -1.0 : 1.0) * norm * d);
            return;
        }
        idx -= 24576;
        if (idx < 1152) stats[idx] = 0.f;
        return;
    }
    int bt = blockIdx.x;
    int iu = threadIdx.x & 127, mh = threadIdx.x >> 7;
    int mi0 = mh * 8;
    float2 acc[8], w[8], st[8];
#pragma unroll
    for (int j = 0; j < 8; ++j) {
        int m = mi0 + j - 15;
        float sy, sx;
        __sincosf(-(float)m * (float)(PI_D / 32.0), &sy, &sx);
        st[j] = make_float2(sx, sy);
        w[j] = make_float2(1.f, 0.f);
        acc[j] = make_float2(0.f, 0.f);
    }
    const float* xrb = xr + (size_t)bt * 8192 + iu;
    const float* xib = xi + (size_t)bt * 8192 + iu;
    for (int p = 0; p < 32; ++p) {
        float a  = xrb[(size_t)p * 128];
        float b  = xib[(size_t)p * 128];
        float a2 = xrb[(size_t)(p + 32) * 128];
        float b2 = xib[(size_t)(p + 32) * 128];
        float sar = a + a2, sai = b + b2;   // for even m
        float dar = a - a2, dai = b - b2;   // for odd m
#pragma unroll
        for (int j = 0; j < 8; ++j) {
            float ur = (j & 1) ? sar : dar;  // j odd -> m even
            float ui = (j & 1) ? sai : dai;
            acc[j].x += ur * w[j].x - ui * w[j].y;
            acc[j].y += ur * w[j].y + ui * w[j].x;
            float nx = w[j].x * st[j].x - w[j].y * st[j].y;
            w[j].y = w[j].x * st[j].y + w[j].y * st[j].x;
            w[j].x = nx;
        }
    }
    __half2* Fb = F + (size_t)bt * 31 * 128 + iu;
#pragma unroll
    for (int j = 0; j < 8; ++j) {
        int mi = mi0 + j;
        if (mi < 31) Fb[(size_t)mi * 128] = __float22half2_rn(acc[j]);
    }
}

// K2: theta contraction. grid (31, 8) = (mi, b), 512 threads (iu, th=t-quarter).
// coeffs written fp16.
__global__ __launch_bounds__(512, 2) void k_theta_in(const __half2* __restrict__ F,
                                                     const float* __restrict__ A_in,
                                                     __half2* __restrict__ coeffs) {
    __shared__ float A[2][16][64];      // 8 KB, zero-padded below |m|
    __shared__ float2 red[2][16][128];  // 32 KB reduction buffer
    int mi = blockIdx.x, b = blockIdx.y;
    int m = mi - 15;
    int am = m < 0 ? -m : m;
    int tid = threadIdx.x;
    for (int idx = tid; idx < 2048; idx += 512) {
        int i = idx >> 10, j = (idx >> 6) & 15, t = idx & 63;
        float v = 0.f;
        if (j >= am) v = A_in[((size_t)i * 256 + (j * j + j + m)) * 64 + t];
        A[i][j][t] = v;
    }
    __syncthreads();
    int iu = tid & 127, th = tid >> 7, i = iu >> 6;
    float2 acc[16];
#pragma unroll
    for (int j = 0; j < 16; ++j) acc[j] = make_float2(0.f, 0.f);
    const __half2* Fb = F + ((size_t)b * 64 * 31 + mi) * 128 + iu;
    for (int tt = 0; tt < 16; ++tt) {
        int t = th * 16 + tt;
        float2 f = __half22float2(Fb[(size_t)t * 31 * 128]);
#pragma unroll
        for (int j = 0; j < 16; ++j) {
            float a = A[i][j][t];
            acc[j].x += a * f.x;
            acc[j].y += a * f.y;
        }
    }
    if (th >= 2) {
#pragma unroll
        for (int j = 0; j < 16; ++j) red[th - 2][j][iu] = acc[j];
    }
    __syncthreads();
    if (th < 2) {
#pragma unroll
        for (int j = 0; j < 16; ++j) {
            float2 r = red[th][j][iu];
            acc[j].x += r.x;
            acc[j].y += r.y;
        }
    }
    __syncthreads();
    if (th == 1) {
#pragma unroll
        for (int j = 0; j < 16; ++j) red[0][j][iu] = acc[j];
    }
    __syncthreads();
    if (th == 0) {
#pragma unroll
        for (int j = 0; j < 16; ++j) {
            if (j >= am) {
                float2 r = red[0][j][iu];
                coeffs[((size_t)b * 256 + (j * j + j + m)) * 128 + iu] =
                    __float22half2_rn(make_float2(acc[j].x + r.x, acc[j].y + r.y));
            }
        }
    }
}

// K3: channel mix. grid (128 kpair, 4 bq), 384 threads = (kk 2)x(s 3)x(dp 64).
// Thread: 2 sd (float2 kernel loads) x 2 b. 4-deep double-buffered pipeline,
// CONTINUOUS across the i=0->1 boundary (flat 32-batch loop). coeffs fp16 in,
// oc fp16 out.
__global__ __launch_bounds__(384, 3) void k_mix(const __half2* __restrict__ coeffs,
                                                const float* __restrict__ kr,
                                                const float* __restrict__ ki,
                                                __half2* __restrict__ oc) {
    __shared__ float2 cs[2][2][128];  // [kk][bb][iu], 4 KB
    int k0 = blockIdx.x * 2;
    int b0 = blockIdx.y * 2;
    int tid = threadIdx.x;
    for (int idx = tid; idx < 512; idx += 384) {
        int kk = idx >> 8, bb = (idx >> 7) & 1, iu = idx & 127;
        cs[kk][bb][iu] =
            __half22float2(coeffs[((size_t)(b0 + bb) * 256 + (k0 + kk)) * 128 + iu]);
    }
    __syncthreads();
    int kk = tid / 192, r = tid % 192;
    int s = r >> 6, dp = r & 63;
    int k = k0 + kk;
    int l = isqrt_k(k);
    float2 acc[2][2];
#pragma unroll
    for (int bb = 0; bb < 2; ++bb) {
        acc[bb][0] = make_float2(0.f, 0.f);
        acc[bb][1] = make_float2(0.f, 0.f);
    }
    // bases for i=0 and i=1 halves
    const float2* krp[2];
    const float2* kip[2];
#pragma unroll
    for (int i = 0; i < 2; ++i) {
        krp[i] = (const float2*)(kr + (size_t)(6 * l + 3 * i + s) * 8192) + dp;
        kip[i] = (const float2*)(ki + (size_t)(6 * l + 3 * i + s) * 8192) + dp;
    }
    float2 w0[4], w1[4];
#pragma unroll
    for (int j = 0; j < 4; ++j) {
        w0[j] = krp[0][(size_t)j * 64];
        w1[j] = kip[0][(size_t)j * 64];
    }
    for (int batch = 0; batch < 32; ++batch) {
        int iu0 = batch * 4;
        float2 n0[4], n1[4];
        if (batch + 1 < 32) {
            int nu = (batch + 1) * 4;
            int bi = nu >> 6, uo = nu & 63;
#pragma unroll
            for (int j = 0; j < 4; ++j) {
                n0[j] = krp[bi][(size_t)(uo + j) * 64];
                n1[j] = kip[bi][(size_t)(uo + j) * 64];
            }
        }
#pragma unroll
        for (int j = 0; j < 4; ++j) {
            int iu = iu0 + j;
            float2 wr = w0[j], wi = w1[j];
#pragma unroll
            for (int bb = 0; bb < 2; ++bb) {
                float2 cv = cs[kk][bb][iu];
                acc[bb][0].x += cv.x * wr.x - cv.y * wi.x;
                acc[bb][0].y += cv.x * wi.x + cv.y * wr.x;
                acc[bb][1].x += cv.x * wr.y - cv.y * wi.y;
                acc[bb][1].y += cv.x * wi.y + cv.y * wr.y;
            }
        }
#pragma unroll
        for (int j = 0; j < 4; ++j) { w0[j] = n0[j]; w1[j] = n1[j]; }
    }
#pragma unroll
    for (int bb = 0; bb < 2; ++bb) {
        size_t o = ((size_t)(b0 + bb) * 256 + k) * 384 + s * 128 + 2 * dp;
        oc[o]     = __float22half2_rn(acc[bb][0]);
        oc[o + 1] = __float22half2_rn(acc[bb][1]);
    }
}

// K4: theta expansion + stats; oc fp16 in, G fp16 out. grid (31, 8), 384 thr.
__global__ __launch_bounds__(384, 2) void k_theta_out(const __half2* __restrict__ oc,
                                                      const float* __restrict__ A_out,
                                                      __half2* __restrict__ G,
                                                      float* __restrict__ ssr,
                                                      float* __restrict__ ssi,
                                                      float* __restrict__ ssq) {
    __shared__ float Ao[3][16][32];  // 6KB
    int mi = blockIdx.x, b = blockIdx.y;
    int m = mi - 15;
    int am = m < 0 ? -m : m;
    int tid = threadIdx.x;
    for (int idx = tid; idx < 1536; idx += 384) {
        int s = idx >> 9, j = (idx >> 5) & 15, t = idx & 31;
        float v = 0.f;
        if (j >= am) v = A_out[((size_t)s * 256 + (j * j + j + m)) * 32 + t];
        Ao[s][j][t] = v;
    }
    __syncthreads();
    int s = tid >> 7;
    float2 c[16];
#pragma unroll
    for (int j = 0; j < 16; ++j) {
        c[j] = make_float2(0.f, 0.f);
        if (j >= am)
            c[j] = __half22float2(oc[((size_t)b * 256 + (j * j + j + m)) * 384 + tid]);
    }
    float sq = 0.f, sr = 0.f, si = 0.f;
    for (int t = 0; t < 32; ++t) {
        float fr = 0.f, fi = 0.f;
#pragma unroll
        for (int j = 0; j < 16; ++j) {
            float a = Ao[s][j][t];
            fr += a * c[j].x;
            fi += a * c[j].y;
        }
        G[(((size_t)b * 32 + t) * 31 + mi) * 384 + tid] =
            __float22half2_rn(make_float2(fr, fi));
        sq += fr * fr + fi * fi;
        if (mi == 15) { sr += fr; si += fi; }
    }
    atomicAdd(&ssq[tid], sq);
    if (mi == 15) {
        atomicAdd(&ssr[tid], sr);
        atomicAdd(&ssi[tid], si);
    }
}

// K5: phi synthesis + BN + gate, radix-2 folded; G fp16 in.
__global__ __launch_bounds__(384, 1) void k_synth_final(const __half2* __restrict__ G,
                                                        const float* __restrict__ ssr,
                                                        const float* __restrict__ ssi,
                                                        const float* __restrict__ ssq,
                                                        const float* __restrict__ gamma,
                                                        const float* __restrict__ betar,
                                                        const float* __restrict__ betai,
                                                        const float* __restrict__ bias,
                                                        float* __restrict__ out) {
    int bt = blockIdx.x;
    int sd = threadIdx.x, s = sd >> 7;
    float2 g[31], st[31];
#pragma unroll
    for (int mi = 0; mi < 31; ++mi) {
        g[mi] = __half22float2(G[((size_t)bt * 31 + mi) * 384 + sd]);
        float sy, sx;
        __sincosf((float)(mi - 15) * (float)(PI_D / 16.0), &sy, &sx);
        st[mi] = make_float2(sx, sy);
    }
    const float invN = 1.0f / 256.0f;
    float mur = 0.f, mui = 0.f;
    if (s == 0) { mur = ssr[sd] * invN; mui = ssi[sd] * invN; }
    float var = ssq[sd] * invN - (mur * mur + mui * mui);
    float scale = gamma[sd] / sqrtf(var + 1e-5f);
    float br = (s == 0) ? betar[sd] : 0.f;
    float bi = (s == 0) ? betai[sd] : 0.f;
    float bb = bias[sd];
    float* ob = out + (size_t)bt * 32 * 384 + sd;
    for (int p = 0; p < 16; ++p) {
        float fr = 0.f, fi = 0.f, fr2 = 0.f, fi2 = 0.f;
#pragma unroll
        for (int mi = 0; mi < 31; ++mi) {
            fr += g[mi].x;
            fi += g[mi].y;
            if (mi & 1) { fr2 += g[mi].x; fi2 += g[mi].y; }  // m even
            else        { fr2 -= g[mi].x; fi2 -= g[mi].y; }  // m odd
        }
        {
            float yr = (fr - mur) * scale + br;
            float yi = (fi - mui) * scale + bi;
            float mag = sqrtf(yr * yr + yi * yi);
            float f = fmaxf(mag + bb, 0.f) / (mag + 1e-6f);
            ob[(size_t)p * 384] = yr * f;
        }
        {
            float yr = (fr2 - mur) * scale + br;
            float yi = (fi2 - mui) * scale + bi;
            float mag = sqrtf(yr * yr + yi * yi);
            float f = fmaxf(mag + bb, 0.f) / (mag + 1e-6f);
            ob[(size_t)(p + 16) * 384] = yr * f;
        }
#pragma unroll
        for (int mi = 0; mi < 31; ++mi) {
            float nx = g[mi].x * st[mi].x - g[mi].y * st[mi].y;
            g[mi].y = g[mi].x * st[mi].y + g[mi].y * st[mi].x;
            g[mi].x = nx;
        }
    }
}

extern "C" void kernel_launch(void* const* d_in, const int* in_sizes, int n_in,
                              void* d_out, int out_size, void* d_ws, size_t ws_size,
                              hipStream_t stream) {
    const float* xr    = (const float*)d_in[0];
    const float* xi    = (const float*)d_in[1];
    const float* kr    = (const float*)d_in[2];
    const float* ki    = (const float*)d_in[3];
    const float* gamma = (const float*)d_in[4];
    const float* betar = (const float*)d_in[5];
    const float* betai = (const float*)d_in[6];
    const float* bias  = (const float*)d_in[7];
    float* out = (float*)d_out;

    char* ws = (char*)d_ws;
    float*   A_in   = (float*)(ws + OFF_A_IN);
    float*   A_out  = (float*)(ws + OFF_A_OUT);
    float*   stats  = (float*)(ws + OFF_STATS);
    float*   ssr    = stats;
    float*   ssi    = stats + 384;
    float*   ssq    = stats + 768;
    __half2* F      = (__half2*)(ws + OFF_R1);  // then oc (fp16)
    __half2* oc     = (__half2*)(ws + OFF_R1);
    __half2* coeffs = (__half2*)(ws + OFF_R2);  // then G (fp16)
    __half2* G      = (__half2*)(ws + OFF_R2);

    k_phi_tables<<<627, 512, 0, stream>>>(xr, xi, F, A_in, A_out, stats);
    k_theta_in<<<dim3(31, 8), 512, 0, stream>>>(F, A_in, coeffs);
    k_mix<<<dim3(128, 4), 384, 0, stream>>>(coeffs, kr, ki, oc);
    k_theta_out<<<dim3(31, 8), 384, 0, stream>>>(oc, A_out, G, ssr, ssi, ssq);
    k_synth_final<<<256, 384, 0, stream>>>(G, ssr, ssi, ssq,
                                           gamma, betar, betai, bias, out);
}

// Round 16
// 179.596 us; speedup vs baseline: 1.1443x; 1.0049x over previous
//
#include <hip/hip_runtime.h>
#include <hip/hip_fp16.h>
#include <math.h>

// SpinSphericalBlock: separable spin-weighted SHT -> channel mix -> inverse SHT
// -> complex BN (spin0 mean, via Parseval on G) -> magnitude-ReLU gating.
//
// Constants: B=8, RES=64, RES_OUT=32, L=15, SPINS_IN=(0,1), SPINS_OUT=(0,1,2),
// C_IN=64, C_OUT=128, NM=31. Output: out_size=3,145,728 float32 = Re(y),
// (b,t,p,s,d) row-major (established R0-R4).
//
// R16 == R15 resubmit (R15 bench hit GPUAcquisitionTimeout; never ran).
// R15 theory (post-mortem R14): kernels invisible under 41us fill floor;
// modeled floors ~30us vs ~135us actual -> latency slack at 1-2 blocks/CU in
// K2/K4/K5. Split each along its parallel axis to double block count:
//   K2: (31,8,2) x 256 thr (iu-half == spin i; LDS 4KB+16KB), (256,4)
//   K4: (31,8,2) x 192 thr (sd-half), (192,4)
//   K5: (256,2)  x 192 thr (sd-half), (192,2)
// K1 and K3 (proven R11 k_mix) untouched.
//
//   K1 k_phi_tables: blocks<512: F[bt,m,iu] = sum_p x e^{-im phi_p} (radix-2)
//                    blocks>=512: Wigner tables (fp64 recurrence) + zero stats
//   K2 k_theta_in:   coeffs[b,k,iu]= sum_t A_in[i,k,t] F[b,t,m(k),iu]
//   K3 k_mix:        oc[b,k,sd]    = sum_iu coeffs * kernel[l(k),i,s,u,d]
//   K4 k_theta_out:  G[bt,m,sd]    = sum_l A_out[s,k,t] oc[b,k,sd]  + stats
//   K5 k_synth_final: y = BN(sum_m G e^{+im phi'_p}) -> gate -> Re(y) (radix-2)

#define PI_D 3.14159265358979323846

// ---------------- workspace layout (bytes) ----------------
#define OFF_A_IN    ((size_t)24320)     // 2*256*64 float    = 131072
#define OFF_A_OUT   ((size_t)155648)    // 3*256*32 float    = 98304
#define OFF_STATS   ((size_t)254208)    // 3*384 float       = 4608
#define OFF_R1      ((size_t)260608)    // F fp16 (8.1MB) then oc fp16 (3.1MB)
#define OFF_R2      ((size_t)25426688)  // coeffs fp16 (1MB) then G fp16 (12.2MB)

// ln(j!) for j=0..30
__constant__ double LF[31] = {
    0.0, 0.0, 0.6931471805599453, 1.791759469228055, 3.1780538303479458,
    4.787491742782046, 6.579251212010101, 8.525161361065415,
    10.604602902745251, 12.801827480081469, 15.104412573075516,
    17.502307845873887, 19.987214495661885, 22.552163853123425,
    25.19122118273868, 27.89927138384089, 30.671860106080672,
    33.50507345013689, 36.39544520803305, 39.339884187199495,
    42.335616460753485, 45.38013889847691, 48.47118135183523,
    51.60667556776438, 54.78472939811232, 58.00360522298052,
    61.261701761002, 64.55753862700634, 67.88974313718154,
    71.25703896716801, 74.65823634883016};

__device__ inline int isqrt_k(int k) {
    int l = (int)sqrtf((float)k + 0.5f);
    while (l * l > k) --l;
    while ((l + 1) * (l + 1) <= k) ++l;
    return l;
}

// d^l_{m,n}(theta) via seed term (1 exp + 2 log) + exact ratio recurrence.
__device__ double wigner_d_rec(int l, int m, int n, double theta) {
    int an = n < 0 ? -n : n;
    int am = m < 0 ? -m : m;
    if (l < an || l < am) return 0.0;
    int kmin = max(0, n - m), kmax = min(l + n, l - m);
    if (kmax < kmin) return 0.0;
    double cb = cos(0.5 * theta), sb = sin(0.5 * theta);
    double pref = 0.5 * (LF[l + m] + LF[l - m] + LF[l + n] + LF[l - n]);
    double lterm = pref
        - (LF[l + n - kmin] + LF[kmin] + LF[m - n + kmin] + LF[l - m - kmin])
        + (double)(2 * l + n - m - 2 * kmin) * log(cb)
        + (double)(m - n + 2 * kmin) * log(sb);
    double term = exp(lterm);
    if ((m - n + kmin) & 1) term = -term;
    double r = (sb * sb) / (cb * cb);
    double acc = term;
    for (int k = kmin; k < kmax; ++k) {
        term *= -((double)((l + n - k) * (l - m - k)) * r)
                / ((double)((k + 1) * (m - n + k + 1)));
        acc += term;
    }
    return acc;
}

// K1: fused phi-DFT (blocks 0..511) + table generation (blocks 512..626).
__global__ __launch_bounds__(512, 2) void k_phi_tables(const float* __restrict__ xr,
                                                       const float* __restrict__ xi,
                                                       __half2* __restrict__ F,
                                                       float* __restrict__ A_in,
                                                       float* __restrict__ A_out,
                                                       float* __restrict__ stats) {
    if (blockIdx.x >= 512) {
        int idx = (blockIdx.x - 512) * 512 + threadIdx.x;
        if (idx < 32768) {
            int t = idx & 63, k = (idx >> 6) & 255, i = idx >> 14;
            int l = isqrt_k(k);
            int m = k - l * l - l;
            double theta = ((double)t + 0.5) * PI_D / 64.0;
            double w = sin(theta) * (PI_D / 64.0) * (2.0 * PI_D / 64.0);
            double norm = sqrt((2.0 * l + 1.0) / (4.0 * PI_D));
            double d = wigner_d_rec(l, m, -i, theta);
            A_in[idx] = (float)(((m & 1) ? -1.0 : 1.0) * norm * w * d);
            return;
        }
        idx -= 32768;
        if (idx < 24576) {
            int t = idx & 31, k = (idx >> 5) & 255, s = idx >> 13;
            int l = isqrt_k(k);
            int m = k - l * l - l;
            double theta = ((double)t + 0.5) * PI_D / 32.0;
            double norm = sqrt((2.0 * l + 1.0) / (4.0 * PI_D));
            double d = wigner_d_rec(l, m, -s, theta);
            A_out[idx] = (float)(((m & 1) ? -1.0 : 1.0) * norm * d);
            return;
        }
        idx -= 24576;
        if (idx < 1152) stats[idx] = 0.f;
        return;
    }
    int bt = blockIdx.x;
    int iu = threadIdx.x & 127, mh = threadIdx.x >> 7;
    int mi0 = mh * 8;
    float2 acc[8], w[8], st[8];
#pragma unroll
    for (int j = 0; j < 8; ++j) {
        int m = mi0 + j - 15;
        float sy, sx;
        __sincosf(-(float)m * (float)(PI_D / 32.0), &sy, &sx);
        st[j] = make_float2(sx, sy);
        w[j] = make_float2(1.f, 0.f);
        acc[j] = make_float2(0.f, 0.f);
    }
    const float* xrb = xr + (size_t)bt * 8192 + iu;
    const float* xib = xi + (size_t)bt * 8192 + iu;
    for (int p = 0; p < 32; ++p) {
        float a  = xrb[(size_t)p * 128];
        float b  = xib[(size_t)p * 128];
        float a2 = xrb[(size_t)(p + 32) * 128];
        float b2 = xib[(size_t)(p + 32) * 128];
        float sar = a + a2, sai = b + b2;   // for even m
        float dar = a - a2, dai = b - b2;   // for odd m
#pragma unroll
        for (int j = 0; j < 8; ++j) {
            float ur = (j & 1) ? sar : dar;  // j odd -> m even
            float ui = (j & 1) ? sai : dai;
            acc[j].x += ur * w[j].x - ui * w[j].y;
            acc[j].y += ur * w[j].y + ui * w[j].x;
            float nx = w[j].x * st[j].x - w[j].y * st[j].y;
            w[j].y = w[j].x * st[j].y + w[j].y * st[j].x;
            w[j].x = nx;
        }
    }
    __half2* Fb = F + (size_t)bt * 31 * 128 + iu;
#pragma unroll
    for (int j = 0; j < 8; ++j) {
        int mi = mi0 + j;
        if (mi < 31) Fb[(size_t)mi * 128] = __float22half2_rn(acc[j]);
    }
}

// K2: theta contraction. grid (31, 8, 2) = (mi, b, iu-half); 256 threads =
// (iu_l 64) x (th 4). iu-half == spin index i, so only one A_in plane staged.
__global__ __launch_bounds__(256, 4) void k_theta_in(const __half2* __restrict__ F,
                                                     const float* __restrict__ A_in,
                                                     __half2* __restrict__ coeffs) {
    __shared__ float A[16][64];        // 4 KB, zero-padded below |m|
    __shared__ float2 red[2][16][64];  // 16 KB reduction buffer
    int mi = blockIdx.x, b = blockIdx.y, z = blockIdx.z;  // z = i
    int m = mi - 15;
    int am = m < 0 ? -m : m;
    int tid = threadIdx.x;
    for (int idx = tid; idx < 1024; idx += 256) {
        int j = idx >> 6, t = idx & 63;
        float v = 0.f;
        if (j >= am) v = A_in[((size_t)z * 256 + (j * j + j + m)) * 64 + t];
        A[j][t] = v;
    }
    __syncthreads();
    int iu_l = tid & 63, th = tid >> 6;
    int iu = z * 64 + iu_l;
    float2 acc[16];
#pragma unroll
    for (int j = 0; j < 16; ++j) acc[j] = make_float2(0.f, 0.f);
    const __half2* Fb = F + ((size_t)b * 64 * 31 + mi) * 128 + iu;
    for (int tt = 0; tt < 16; ++tt) {
        int t = th * 16 + tt;
        float2 f = __half22float2(Fb[(size_t)t * 31 * 128]);
#pragma unroll
        for (int j = 0; j < 16; ++j) {
            float a = A[j][t];
            acc[j].x += a * f.x;
            acc[j].y += a * f.y;
        }
    }
    if (th >= 2) {
#pragma unroll
        for (int j = 0; j < 16; ++j) red[th - 2][j][iu_l] = acc[j];
    }
    __syncthreads();
    if (th < 2) {
#pragma unroll
        for (int j = 0; j < 16; ++j) {
            float2 r = red[th][j][iu_l];
            acc[j].x += r.x;
            acc[j].y += r.y;
        }
    }
    __syncthreads();
    if (th == 1) {
#pragma unroll
        for (int j = 0; j < 16; ++j) red[0][j][iu_l] = acc[j];
    }
    __syncthreads();
    if (th == 0) {
#pragma unroll
        for (int j = 0; j < 16; ++j) {
            if (j >= am) {
                float2 r = red[0][j][iu_l];
                coeffs[((size_t)b * 256 + (j * j + j + m)) * 128 + iu] =
                    __float22half2_rn(make_float2(acc[j].x + r.x, acc[j].y + r.y));
            }
        }
    }
}

// K3: channel mix (proven R11/R14 structure). grid (128 kpair, 4 bq),
// 384 threads = (kk 2)x(s 3)x(dp 64); 4-deep pipeline, flat 32-batch loop.
__global__ __launch_bounds__(384, 3) void k_mix(const __half2* __restrict__ coeffs,
                                                const float* __restrict__ kr,
                                                const float* __restrict__ ki,
                                                __half2* __restrict__ oc) {
    __shared__ float2 cs[2][2][128];  // [kk][bb][iu], 4 KB
    int k0 = blockIdx.x * 2;
    int b0 = blockIdx.y * 2;
    int tid = threadIdx.x;
    for (int idx = tid; idx < 512; idx += 384) {
        int kk = idx >> 8, bb = (idx >> 7) & 1, iu = idx & 127;
        cs[kk][bb][iu] =
            __half22float2(coeffs[((size_t)(b0 + bb) * 256 + (k0 + kk)) * 128 + iu]);
    }
    __syncthreads();
    int kk = tid / 192, r = tid % 192;
    int s = r >> 6, dp = r & 63;
    int k = k0 + kk;
    int l = isqrt_k(k);
    float2 acc[2][2];
#pragma unroll
    for (int bb = 0; bb < 2; ++bb) {
        acc[bb][0] = make_float2(0.f, 0.f);
        acc[bb][1] = make_float2(0.f, 0.f);
    }
    const float2* krp[2];
    const float2* kip[2];
#pragma unroll
    for (int i = 0; i < 2; ++i) {
        krp[i] = (const float2*)(kr + (size_t)(6 * l + 3 * i + s) * 8192) + dp;
        kip[i] = (const float2*)(ki + (size_t)(6 * l + 3 * i + s) * 8192) + dp;
    }
    float2 w0[4], w1[4];
#pragma unroll
    for (int j = 0; j < 4; ++j) {
        w0[j] = krp[0][(size_t)j * 64];
        w1[j] = kip[0][(size_t)j * 64];
    }
    for (int batch = 0; batch < 32; ++batch) {
        int iu0 = batch * 4;
        float2 n0[4], n1[4];
        if (batch + 1 < 32) {
            int nu = (batch + 1) * 4;
            int bi = nu >> 6, uo = nu & 63;
#pragma unroll
            for (int j = 0; j < 4; ++j) {
                n0[j] = krp[bi][(size_t)(uo + j) * 64];
                n1[j] = kip[bi][(size_t)(uo + j) * 64];
            }
        }
#pragma unroll
        for (int j = 0; j < 4; ++j) {
            int iu = iu0 + j;
            float2 wr = w0[j], wi = w1[j];
#pragma unroll
            for (int bb = 0; bb < 2; ++bb) {
                float2 cv = cs[kk][bb][iu];
                acc[bb][0].x += cv.x * wr.x - cv.y * wi.x;
                acc[bb][0].y += cv.x * wi.x + cv.y * wr.x;
                acc[bb][1].x += cv.x * wr.y - cv.y * wi.y;
                acc[bb][1].y += cv.x * wi.y + cv.y * wr.y;
            }
        }
#pragma unroll
        for (int j = 0; j < 4; ++j) { w0[j] = n0[j]; w1[j] = n1[j]; }
    }
#pragma unroll
    for (int bb = 0; bb < 2; ++bb) {
        size_t o = ((size_t)(b0 + bb) * 256 + k) * 384 + s * 128 + 2 * dp;
        oc[o]     = __float22half2_rn(acc[bb][0]);
        oc[o + 1] = __float22half2_rn(acc[bb][1]);
    }
}

// K4: theta expansion + stats. grid (31, 8, 2) = (mi, b, sd-half); 192 threads.
__global__ __launch_bounds__(192, 4) void k_theta_out(const __half2* __restrict__ oc,
                                                      const float* __restrict__ A_out,
                                                      __half2* __restrict__ G,
                                                      float* __restrict__ ssr,
                                                      float* __restrict__ ssi,
                                                      float* __restrict__ ssq) {
    __shared__ float Ao[3][16][32];  // 6KB
    int mi = blockIdx.x, b = blockIdx.y, z = blockIdx.z;
    int m = mi - 15;
    int am = m < 0 ? -m : m;
    int tid = threadIdx.x;
    for (int idx = tid; idx < 1536; idx += 192) {
        int s = idx >> 9, j = (idx >> 5) & 15, t = idx & 31;
        float v = 0.f;
        if (j >= am) v = A_out[((size_t)s * 256 + (j * j + j + m)) * 32 + t];
        Ao[s][j][t] = v;
    }
    __syncthreads();
    int sd = z * 192 + tid;
    int s = sd >> 7;
    float2 c[16];
#pragma unroll
    for (int j = 0; j < 16; ++j) {
        c[j] = make_float2(0.f, 0.f);
        if (j >= am)
            c[j] = __half22float2(oc[((size_t)b * 256 + (j * j + j + m)) * 384 + sd]);
    }
    float sq = 0.f, sr = 0.f, si = 0.f;
    for (int t = 0; t < 32; ++t) {
        float fr = 0.f, fi = 0.f;
#pragma unroll
        for (int j = 0; j < 16; ++j) {
            float a = Ao[s][j][t];
            fr += a * c[j].x;
            fi += a * c[j].y;
        }
        G[(((size_t)b * 32 + t) * 31 + mi) * 384 + sd] =
            __float22half2_rn(make_float2(fr, fi));
        sq += fr * fr + fi * fi;
        if (mi == 15) { sr += fr; si += fi; }
    }
    atomicAdd(&ssq[sd], sq);
    if (mi == 15) {
        atomicAdd(&ssr[sd], sr);
        atomicAdd(&ssi[sd], si);
    }
}

// K5: phi synthesis + BN + gate, radix-2 folded. grid (256 bt, 2 sd-half),
// 192 threads. Rotation state (g[31]+st[31]) in registers; (192,2) caps 256.
__global__ __launch_bounds__(192, 2) void k_synth_final(const __half2* __restrict__ G,
                                                        const float* __restrict__ ssr,
                                                        const float* __restrict__ ssi,
                                                        const float* __restrict__ ssq,
                                                        const float* __restrict__ gamma,
                                                        const float* __restrict__ betar,
                                                        const float* __restrict__ betai,
                                                        const float* __restrict__ bias,
                                                        float* __restrict__ out) {
    int bt = blockIdx.x;
    int sd = blockIdx.y * 192 + threadIdx.x;
    int s = sd >> 7;
    float2 g[31], st[31];
#pragma unroll
    for (int mi = 0; mi < 31; ++mi) {
        g[mi] = __half22float2(G[((size_t)bt * 31 + mi) * 384 + sd]);
        float sy, sx;
        __sincosf((float)(mi - 15) * (float)(PI_D / 16.0), &sy, &sx);
        st[mi] = make_float2(sx, sy);
    }
    const float invN = 1.0f / 256.0f;
    float mur = 0.f, mui = 0.f;
    if (s == 0) { mur = ssr[sd] * invN; mui = ssi[sd] * invN; }
    float var = ssq[sd] * invN - (mur * mur + mui * mui);
    float scale = gamma[sd] / sqrtf(var + 1e-5f);
    float br = (s == 0) ? betar[sd] : 0.f;
    float bi = (s == 0) ? betai[sd] : 0.f;
    float bb = bias[sd];
    float* ob = out + (size_t)bt * 32 * 384 + sd;
    for (int p = 0; p < 16; ++p) {
        float fr = 0.f, fi = 0.f, fr2 = 0.f, fi2 = 0.f;
#pragma unroll
        for (int mi = 0; mi < 31; ++mi) {
            fr += g[mi].x;
            fi += g[mi].y;
            if (mi & 1) { fr2 += g[mi].x; fi2 += g[mi].y; }  // m even
            else        { fr2 -= g[mi].x; fi2 -= g[mi].y; }  // m odd
        }
        {
            float yr = (fr - mur) * scale + br;
            float yi = (fi - mui) * scale + bi;
            float mag = sqrtf(yr * yr + yi * yi);
            float f = fmaxf(mag + bb, 0.f) / (mag + 1e-6f);
            ob[(size_t)p * 384] = yr * f;
        }
        {
            float yr = (fr2 - mur) * scale + br;
            float yi = (fi2 - mui) * scale + bi;
            float mag = sqrtf(yr * yr + yi * yi);
            float f = fmaxf(mag + bb, 0.f) / (mag + 1e-6f);
            ob[(size_t)(p + 16) * 384] = yr * f;
        }
#pragma unroll
        for (int mi = 0; mi < 31; ++mi) {
            float nx = g[mi].x * st[mi].x - g[mi].y * st[mi].y;
            g[mi].y = g[mi].x * st[mi].y + g[mi].y * st[mi].x;
            g[mi].x = nx;
        }
    }
}

extern "C" void kernel_launch(void* const* d_in, const int* in_sizes, int n_in,
                              void* d_out, int out_size, void* d_ws, size_t ws_size,
                              hipStream_t stream) {
    const float* xr    = (const float*)d_in[0];
    const float* xi    = (const float*)d_in[1];
    const float* kr    = (const float*)d_in[2];
    const float* ki    = (const float*)d_in[3];
    const float* gamma = (const float*)d_in[4];
    const float* betar = (const float*)d_in[5];
    const float* betai = (const float*)d_in[6];
    const float* bias  = (const float*)d_in[7];
    float* out = (float*)d_out;

    char* ws = (char*)d_ws;
    float*   A_in   = (float*)(ws + OFF_A_IN);
    float*   A_out  = (float*)(ws + OFF_A_OUT);
    float*   stats  = (float*)(ws + OFF_STATS);
    float*   ssr    = stats;
    float*   ssi    = stats + 384;
    float*   ssq    = stats + 768;
    __half2* F      = (__half2*)(ws + OFF_R1);  // then oc (fp16)
    __half2* oc     = (__half2*)(ws + OFF_R1);
    __half2* coeffs = (__half2*)(ws + OFF_R2);  // then G (fp16)
    __half2* G      = (__half2*)(ws + OFF_R2);

    k_phi_tables<<<627, 512, 0, stream>>>(xr, xi, F, A_in, A_out, stats);
    k_theta_in<<<dim3(31, 8, 2), 256, 0, stream>>>(F, A_in, coeffs);
    k_mix<<<dim3(128, 4), 384, 0, stream>>>(coeffs, kr, ki, oc);
    k_theta_out<<<dim3(31, 8, 2), 192, 0, stream>>>(oc, A_out, G, ssr, ssi, ssq);
    k_synth_final<<<dim3(256, 2), 192, 0, stream>>>(G, ssr, ssi, ssq,
                                                    gamma, betar, betai, bias, out);
}